// Round 1
// baseline (399.970 us; speedup 1.0000x reference)
//
#include <hip/hip_runtime.h>

#define D 128            // D_IN == D_OUT == 128
constexpr int BM  = 64;  // GEMM rows per block
constexpr int BK  = 32;  // GEMM k-tile
constexpr int EPB = 512; // SpMM edges per block

// ---------------------------------------------------------------------------
// GEMM: XW[M][128] = X[M][128] @ W[128][128], fp32 vector ALU.
// Block: 256 threads as 16x16; each thread computes 4 rows x 8 cols.
// ---------------------------------------------------------------------------
__global__ __launch_bounds__(256) void gemm_xw(const float* __restrict__ X,
                                               const float* __restrict__ W,
                                               float* __restrict__ XW, int M) {
    // Xs transposed [k][m], +1 pad so the 32-lane transposing write hits
    // distinct banks (bank = (kk + r) % 32).
    __shared__ float Xs[BK][BM + 1];
    __shared__ float Ws[BK][D];

    const int block_row = blockIdx.x * BM;
    const int t  = threadIdx.x;
    const int tx = t & 15;   // col group: cols tx*8 .. tx*8+7
    const int ty = t >> 4;   // row group: rows ty*4 .. ty*4+3

    float acc[4][8] = {};

    for (int k0 = 0; k0 < D; k0 += BK) {
        // Load X tile (BM x BK), store transposed. 2048 elems / 256 thr = 8 ea.
        const int kk = t & 31;       // k within tile
        const int rr = t >> 5;       // row subgroup 0..7
#pragma unroll
        for (int p = 0; p < 8; ++p) {
            const int r  = p * 8 + rr;
            const int gr = block_row + r;
            float v = 0.f;
            if (gr < M) v = X[gr * D + k0 + kk];
            Xs[kk][r] = v;
        }
        // Load W tile (BK x D) = 4096 / 256 = 16 each, coalesced.
#pragma unroll
        for (int p = 0; p < 16; ++p) {
            const int idx = p * 256 + t;
            Ws[idx >> 7][idx & 127] = W[(k0 + (idx >> 7)) * D + (idx & 127)];
        }
        __syncthreads();

#pragma unroll
        for (int k = 0; k < BK; ++k) {
            float a[4], b[8];
#pragma unroll
            for (int i = 0; i < 4; ++i) a[i] = Xs[k][ty * 4 + i];
            const float4 b0 = *(const float4*)&Ws[k][tx * 8];
            const float4 b1 = *(const float4*)&Ws[k][tx * 8 + 4];
            b[0]=b0.x; b[1]=b0.y; b[2]=b0.z; b[3]=b0.w;
            b[4]=b1.x; b[5]=b1.y; b[6]=b1.z; b[7]=b1.w;
#pragma unroll
            for (int i = 0; i < 4; ++i)
#pragma unroll
                for (int j = 0; j < 8; ++j)
                    acc[i][j] += a[i] * b[j];
        }
        __syncthreads();
    }

    // Store: two float4 per row.
#pragma unroll
    for (int i = 0; i < 4; ++i) {
        const int gr = block_row + ty * 4 + i;
        if (gr < M) {
            float4* dst = (float4*)(XW + gr * D + tx * 8);
            dst[0] = make_float4(acc[i][0], acc[i][1], acc[i][2], acc[i][3]);
            dst[1] = make_float4(acc[i][4], acc[i][5], acc[i][6], acc[i][7]);
        }
    }
}

// ---------------------------------------------------------------------------
// SpMM: out = A @ XW with sorted edge_rows.
// One block = 128 threads (thread t owns output column t), EPB edges.
// Register-accumulate runs of equal row; atomicAdd on row change / at ends.
// ---------------------------------------------------------------------------
__global__ __launch_bounds__(128) void spmm_edges(const float* __restrict__ XW,
                                                  const int* __restrict__ rows,
                                                  const int* __restrict__ cols,
                                                  const float* __restrict__ vals,
                                                  float* __restrict__ out,
                                                  int nEdges) {
    __shared__ int   s_row[EPB];
    __shared__ int   s_col[EPB];
    __shared__ float s_val[EPB];

    const int e0 = blockIdx.x * EPB;
    const int t  = threadIdx.x;       // column index 0..127
    const int n  = min(EPB, nEdges - e0);

    for (int i = t; i < n; i += 128) {
        s_row[i] = rows[e0 + i];
        s_col[i] = cols[e0 + i];
        s_val[i] = vals[e0 + i];
    }
    __syncthreads();

    float acc = 0.f;
    int   cur = s_row[0];
    for (int i = 0; i < n; ++i) {
        const int   r = s_row[i];   // LDS broadcast (uniform) — free
        const int   c = s_col[i];
        const float v = s_val[i];
        if (r != cur) {             // block-uniform branch
            atomicAdd(&out[cur * D + t], acc);
            acc = 0.f;
            cur = r;
        }
        acc += v * XW[c * D + t];   // coalesced 512B gather, L2/L3-resident
    }
    atomicAdd(&out[cur * D + t], acc);
}

// ---------------------------------------------------------------------------
extern "C" void kernel_launch(void* const* d_in, const int* in_sizes, int n_in,
                              void* d_out, int out_size, void* d_ws, size_t ws_size,
                              hipStream_t stream) {
    const float* X    = (const float*)d_in[0];
    const float* W    = (const float*)d_in[1];
    const int*   rows = (const int*)d_in[2];
    const int*   cols = (const int*)d_in[3];
    const float* vals = (const float*)d_in[4];
    float*       out  = (float*)d_out;
    float*       XW   = (float*)d_ws;   // 100000*128*4 = 51.2 MB scratch

    const int M = in_sizes[0] / D;      // 100000
    const int E = in_sizes[2];          // 1600000

    // Output must start at zero (poisoned with 0xAA; zero-degree rows stay 0).
    hipMemsetAsync(d_out, 0, (size_t)out_size * sizeof(float), stream);

    gemm_xw<<<dim3((M + BM - 1) / BM), 256, 0, stream>>>(X, W, XW, M);

    spmm_edges<<<dim3((E + EPB - 1) / EPB), 128, 0, stream>>>(XW, rows, cols,
                                                              vals, out, E);
}

// Round 3
// 230.125 us; speedup vs baseline: 1.7381x; 1.7381x over previous
//
#include <hip/hip_runtime.h>

#define D 128

typedef __attribute__((ext_vector_type(8))) short bf16x8;
typedef __attribute__((ext_vector_type(4))) float f32x4;

__device__ __forceinline__ ushort f2bf(float f) {   // round-to-nearest-even
    unsigned u = __float_as_uint(f);
    u += 0x7fffu + ((u >> 16) & 1u);
    return (ushort)(u >> 16);
}
__device__ __forceinline__ float bf2f(ushort h) {
    return __uint_as_float(((unsigned)h) << 16);
}

// ---------------------------------------------------------------------------
// W[k][c] (fp32) -> Wt[c][k] (bf16). 16384 elems, trivial.
// ---------------------------------------------------------------------------
__global__ __launch_bounds__(256) void convert_wt(const float* __restrict__ W,
                                                  ushort* __restrict__ Wt) {
    int idx = blockIdx.x * 256 + threadIdx.x;   // 0..16383
    int c = idx >> 7, k = idx & 127;
    Wt[c * D + k] = f2bf(W[k * D + c]);
}

// ---------------------------------------------------------------------------
// row_ptr[r] = lower_bound(rows, r), r in [0, N]. rows is sorted.
// ---------------------------------------------------------------------------
__global__ __launch_bounds__(256) void build_rowptr(const int* __restrict__ rows,
                                                    int E, int* __restrict__ rp,
                                                    int N) {
    int r = blockIdx.x * 256 + threadIdx.x;
    if (r > N) return;
    int lo = 0, hi = E;
    while (lo < hi) {
        int mid = (lo + hi) >> 1;
        if (rows[mid] < r) lo = mid + 1; else hi = mid;
    }
    rp[r] = lo;
}

// ---------------------------------------------------------------------------
// XW(bf16)[M][128] = X(fp32)[M][128] @ W. MFMA 16x16x32 bf16.
// Block = 256 thr = 4 waves; block tile 64 rows x 128 cols, full K=128.
// Each wave: 16 rows x 128 cols = 8 col-tiles x 4 k-steps = 32 MFMAs.
// ---------------------------------------------------------------------------
__global__ __launch_bounds__(256) void gemm_mfma(const float* __restrict__ X,
                                                 const ushort* __restrict__ Wt,
                                                 ushort* __restrict__ XW, int M) {
    __shared__ ushort Wl[D][D + 8];   // +8 ushort pad: row stride 272B (17*16)

    const int t = threadIdx.x;
    // Stage Wt (128x128 bf16 = 32KB = 2048 8-ushort chunks) into padded LDS.
#pragma unroll
    for (int p = 0; p < 8; ++p) {
        int idx = p * 256 + t;          // 0..2047
        int row = idx >> 4, ch = idx & 15;   // 16 chunks per 128-elem row
        *(uint4*)&Wl[row][ch * 8] = *(const uint4*)&Wt[row * D + ch * 8];
    }
    __syncthreads();

    const int lane = t & 63, wid = t >> 6;
    const int r0 = blockIdx.x * 64 + wid * 16;

    int arow = r0 + (lane & 15);
    if (arow >= M) arow = M - 1;                      // clamp; stores guarded
    const float* xp = X + (size_t)arow * D + ((lane >> 4) * 8);

    bf16x8 a[4];
#pragma unroll
    for (int ks = 0; ks < 4; ++ks) {
        float4 f0 = *(const float4*)(xp + ks * 32);
        float4 f1 = *(const float4*)(xp + ks * 32 + 4);
        bf16x8 av;
        av[0] = (short)f2bf(f0.x); av[1] = (short)f2bf(f0.y);
        av[2] = (short)f2bf(f0.z); av[3] = (short)f2bf(f0.w);
        av[4] = (short)f2bf(f1.x); av[5] = (short)f2bf(f1.y);
        av[6] = (short)f2bf(f1.z); av[7] = (short)f2bf(f1.w);
        a[ks] = av;
    }

    f32x4 acc[8];
#pragma unroll
    for (int jt = 0; jt < 8; ++jt) acc[jt] = (f32x4){0.f, 0.f, 0.f, 0.f};

#pragma unroll
    for (int jt = 0; jt < 8; ++jt) {
        const ushort* bp = &Wl[jt * 16 + (lane & 15)][(lane >> 4) * 8];
#pragma unroll
        for (int ks = 0; ks < 4; ++ks) {
            bf16x8 b = *(const bf16x8*)(bp + ks * 32);
            acc[jt] = __builtin_amdgcn_mfma_f32_16x16x32_bf16(a[ks], b, acc[jt],
                                                              0, 0, 0);
        }
    }

    // C/D layout (HW-verified): col = lane&15, row = (lane>>4)*4 + reg.
#pragma unroll
    for (int jt = 0; jt < 8; ++jt) {
#pragma unroll
        for (int q = 0; q < 4; ++q) {
            int rr = r0 + (lane >> 4) * 4 + q;
            if (rr < M)
                XW[(size_t)rr * D + jt * 16 + (lane & 15)] = f2bf(acc[jt][q]);
        }
    }
}

// ---------------------------------------------------------------------------
// CSR SpMM: one wave per output row; lane owns 2 bf16 cols (ushort2 = 4B).
// Gather = 64 lanes x 4B = 256B coalesced per edge. No atomics, no memset.
// ---------------------------------------------------------------------------
__global__ __launch_bounds__(256) void spmm_csr(const ushort* __restrict__ XW,
                                                const int* __restrict__ rp,
                                                const int* __restrict__ cols,
                                                const float* __restrict__ vals,
                                                float* __restrict__ out, int N) {
    const int lane = threadIdx.x & 63;
    const int r = blockIdx.x * 4 + (threadIdx.x >> 6);
    if (r >= N) return;

    const int s = rp[r], e = rp[r + 1];
    const uint* base = (const uint*)XW;   // elem c*64 + lane = 2 bf16 cols
    float ax = 0.f, ay = 0.f;

    int i = s;
    for (; i + 1 < e; i += 2) {          // unroll-2: two gathers in flight
        int   c0 = cols[i],     c1 = cols[i + 1];
        float v0 = vals[i],     v1 = vals[i + 1];
        uint  u0 = base[(size_t)c0 * 64 + lane];
        uint  u1 = base[(size_t)c1 * 64 + lane];
        ax += v0 * bf2f((ushort)(u0 & 0xffff));
        ay += v0 * bf2f((ushort)(u0 >> 16));
        ax += v1 * bf2f((ushort)(u1 & 0xffff));
        ay += v1 * bf2f((ushort)(u1 >> 16));
    }
    if (i < e) {
        int   c = cols[i];
        float v = vals[i];
        uint  u = base[(size_t)c * 64 + lane];
        ax += v * bf2f((ushort)(u & 0xffff));
        ay += v * bf2f((ushort)(u >> 16));
    }
    ((float2*)out)[(size_t)r * 64 + lane] = make_float2(ax, ay);
}

// ---------------------------------------------------------------------------
extern "C" void kernel_launch(void* const* d_in, const int* in_sizes, int n_in,
                              void* d_out, int out_size, void* d_ws, size_t ws_size,
                              hipStream_t stream) {
    const float* X    = (const float*)d_in[0];
    const float* W    = (const float*)d_in[1];
    const int*   rows = (const int*)d_in[2];
    const int*   cols = (const int*)d_in[3];
    const float* vals = (const float*)d_in[4];
    float*       out  = (float*)d_out;

    const int M = in_sizes[0] / D;      // 100000 nodes
    const int E = in_sizes[2];          // 1600000 edges

    // Workspace layout (poisoned each call; everything fully overwritten):
    //   [0, 25.6MB)              XW bf16 [M][128]
    //   [+0, +400,004)           row_ptr int[M+1]
    //   [+pad16, +32,768)        Wt bf16 [128][128]
    char* ws = (char*)d_ws;
    ushort* XWb = (ushort*)ws;
    int*    rp  = (int*)(ws + (size_t)M * D * sizeof(ushort));
    ushort* Wt  = (ushort*)(ws + (size_t)M * D * sizeof(ushort)
                               + (((size_t)(M + 1) * sizeof(int) + 15) & ~(size_t)15));

    convert_wt  <<<64, 256, 0, stream>>>(W, Wt);
    build_rowptr<<<(M + 256) / 256, 256, 0, stream>>>(rows, E, rp, M);
    gemm_mfma   <<<(M + 63) / 64, 256, 0, stream>>>(X, Wt, XWb, M);
    spmm_csr    <<<(M + 3) / 4, 256, 0, stream>>>(XWb, rp, cols, vals, out, M);
}

// Round 4
// 209.452 us; speedup vs baseline: 1.9096x; 1.0987x over previous
//
#include <hip/hip_runtime.h>

#define D 128

typedef __attribute__((ext_vector_type(8))) short bf16x8;
typedef __attribute__((ext_vector_type(4))) float f32x4;

__device__ __forceinline__ ushort f2bf(float f) {   // round-to-nearest-even
    unsigned u = __float_as_uint(f);
    u += 0x7fffu + ((u >> 16) & 1u);
    return (ushort)(u >> 16);
}
__device__ __forceinline__ float bf2f(ushort h) {
    return __uint_as_float(((unsigned)h) << 16);
}

// ---------------------------------------------------------------------------
// W[k][c] fp32 -> Wf bf16 in MFMA A-fragment order:
//   Wf[(((jt*4+ks)*64 + lane)*8 + j)] = W[k][col],
//   col = jt*16 + (lane&15),  k = ks*32 + (lane>>4)*8 + j.
// So gemm's per-lane fragment load is contiguous 16B at ((jt*4+ks)*64+lane)*16B.
// ---------------------------------------------------------------------------
__global__ __launch_bounds__(256) void convert_wf(const float* __restrict__ W,
                                                  ushort* __restrict__ Wf) {
    int idx = blockIdx.x * 256 + threadIdx.x;   // 0..16383
    int j    = idx & 7;
    int lane = (idx >> 3) & 63;
    int f    = idx >> 9;            // 0..31 = jt*4 + ks
    int jt = f >> 2, ks = f & 3;
    int col = jt * 16 + (lane & 15);
    int k   = ks * 32 + ((lane >> 4) * 8) + j;
    Wf[idx] = f2bf(W[k * D + col]);
}

// ---------------------------------------------------------------------------
// row_ptr[r] = lower_bound(rows, r), r in [0, N]. rows is sorted.
// ---------------------------------------------------------------------------
__global__ __launch_bounds__(256) void build_rowptr(const int* __restrict__ rows,
                                                    int E, int* __restrict__ rp,
                                                    int N) {
    int r = blockIdx.x * 256 + threadIdx.x;
    if (r > N) return;
    int lo = 0, hi = E;
    while (lo < hi) {
        int mid = (lo + hi) >> 1;
        if (rows[mid] < r) lo = mid + 1; else hi = mid;
    }
    rp[r] = lo;
}

// ---------------------------------------------------------------------------
// XW(bf16) = X(fp32) @ W via mfma_f32_16x16x32_bf16, operands SWAPPED:
//   A-operand = W fragment (m = out col), B-operand = X fragment (n = out row)
//   => D: lane&15 = XW row, (lane>>4)*4+reg = 4 consecutive XW cols.
// No LDS, no syncthreads. Wf (32KB) is L1-resident; X streamed.
// Block 256 thr = 4 waves x 16 rows = 64 rows.
// ---------------------------------------------------------------------------
__global__ __launch_bounds__(256) void gemm_mfma(const float* __restrict__ X,
                                                 const ushort* __restrict__ Wf,
                                                 ushort* __restrict__ XW, int M) {
    const int t = threadIdx.x, lane = t & 63, wid = t >> 6;
    const int r0 = blockIdx.x * 64 + wid * 16;

    int arow = r0 + (lane & 15);
    if (arow >= M) arow = M - 1;                 // clamp; stores guarded
    const float* xp = X + (size_t)arow * D + ((lane >> 4) * 8);

    bf16x8 xf[4];
#pragma unroll
    for (int ks = 0; ks < 4; ++ks) {
        float4 f0 = *(const float4*)(xp + ks * 32);
        float4 f1 = *(const float4*)(xp + ks * 32 + 4);
        bf16x8 av;
        av[0] = (short)f2bf(f0.x); av[1] = (short)f2bf(f0.y);
        av[2] = (short)f2bf(f0.z); av[3] = (short)f2bf(f0.w);
        av[4] = (short)f2bf(f1.x); av[5] = (short)f2bf(f1.y);
        av[6] = (short)f2bf(f1.z); av[7] = (short)f2bf(f1.w);
        xf[ks] = av;
    }

    const bf16x8* wf = (const bf16x8*)Wf + lane;   // + (jt*4+ks)*64

    f32x4 acc[8];
#pragma unroll
    for (int jt = 0; jt < 8; ++jt) acc[jt] = (f32x4){0.f, 0.f, 0.f, 0.f};

#pragma unroll
    for (int jt = 0; jt < 8; ++jt)
#pragma unroll
        for (int ks = 0; ks < 4; ++ks) {
            bf16x8 w = wf[(jt * 4 + ks) * 64];
            acc[jt] = __builtin_amdgcn_mfma_f32_16x16x32_bf16(w, xf[ks],
                                                              acc[jt], 0, 0, 0);
        }

    const int row = r0 + (lane & 15);
    if (row < M) {
        uint* dst = (uint*)(XW + (size_t)row * D + (lane >> 4) * 4);
#pragma unroll
        for (int jt = 0; jt < 8; ++jt) {
            uint lo = (uint)f2bf(acc[jt][0]) | ((uint)f2bf(acc[jt][1]) << 16);
            uint hi = (uint)f2bf(acc[jt][2]) | ((uint)f2bf(acc[jt][3]) << 16);
            uint* p = dst + jt * 8;                 // jt*16 elems = 8 uints
            p[0] = lo; p[1] = hi;
        }
    }
}

// ---------------------------------------------------------------------------
// CSR SpMM: one wave per output row; lane owns 2 bf16 cols (4B gather/lane).
// Unroll-4: 4 independent gathers in flight per wave (latency-bound fix).
// ---------------------------------------------------------------------------
__global__ __launch_bounds__(256) void spmm_csr(const ushort* __restrict__ XW,
                                                const int* __restrict__ rp,
                                                const int* __restrict__ cols,
                                                const float* __restrict__ vals,
                                                float* __restrict__ out, int N) {
    const int lane = threadIdx.x & 63;
    const int r = blockIdx.x * 4 + (threadIdx.x >> 6);
    if (r >= N) return;

    const int s = rp[r], e = rp[r + 1];
    const uint* base = (const uint*)XW;   // elem c*64 + lane = 2 bf16 cols
    float ax = 0.f, ay = 0.f;

    int i = s;
    for (; i + 3 < e; i += 4) {
        int   c0 = cols[i],     c1 = cols[i + 1];
        int   c2 = cols[i + 2], c3 = cols[i + 3];
        float v0 = vals[i],     v1 = vals[i + 1];
        float v2 = vals[i + 2], v3 = vals[i + 3];
        uint  u0 = base[(size_t)c0 * 64 + lane];
        uint  u1 = base[(size_t)c1 * 64 + lane];
        uint  u2 = base[(size_t)c2 * 64 + lane];
        uint  u3 = base[(size_t)c3 * 64 + lane];
        ax += v0 * bf2f((ushort)(u0 & 0xffff));
        ay += v0 * bf2f((ushort)(u0 >> 16));
        ax += v1 * bf2f((ushort)(u1 & 0xffff));
        ay += v1 * bf2f((ushort)(u1 >> 16));
        ax += v2 * bf2f((ushort)(u2 & 0xffff));
        ay += v2 * bf2f((ushort)(u2 >> 16));
        ax += v3 * bf2f((ushort)(u3 & 0xffff));
        ay += v3 * bf2f((ushort)(u3 >> 16));
    }
    for (; i < e; ++i) {
        int   c = cols[i];
        float v = vals[i];
        uint  u = base[(size_t)c * 64 + lane];
        ax += v * bf2f((ushort)(u & 0xffff));
        ay += v * bf2f((ushort)(u >> 16));
    }
    ((float2*)out)[(size_t)r * 64 + lane] = make_float2(ax, ay);
}

// ---------------------------------------------------------------------------
extern "C" void kernel_launch(void* const* d_in, const int* in_sizes, int n_in,
                              void* d_out, int out_size, void* d_ws, size_t ws_size,
                              hipStream_t stream) {
    const float* X    = (const float*)d_in[0];
    const float* W    = (const float*)d_in[1];
    const int*   rows = (const int*)d_in[2];
    const int*   cols = (const int*)d_in[3];
    const float* vals = (const float*)d_in[4];
    float*       out  = (float*)d_out;

    const int M = in_sizes[0] / D;      // 100000 nodes
    const int E = in_sizes[2];          // 1600000 edges

    // Workspace layout (poisoned each call; everything fully overwritten):
    //   [0, 25.6MB)       XW bf16 [M][128]
    //   [+0, +400,004)    row_ptr int[M+1]
    //   [+pad16, +32KB)   Wf bf16 fragment-ordered [16384]
    char* ws = (char*)d_ws;
    ushort* XWb = (ushort*)ws;
    int*    rp  = (int*)(ws + (size_t)M * D * sizeof(ushort));
    ushort* Wf  = (ushort*)(ws + (size_t)M * D * sizeof(ushort)
                               + (((size_t)(M + 1) * sizeof(int) + 15) & ~(size_t)15));

    convert_wf  <<<64, 256, 0, stream>>>(W, Wf);
    build_rowptr<<<(M + 256) / 256, 256, 0, stream>>>(rows, E, rp, M);
    gemm_mfma   <<<(M + 63) / 64, 256, 0, stream>>>(X, Wf, XWb, M);
    spmm_csr    <<<(M + 3) / 4, 256, 0, stream>>>(XWb, rp, cols, vals, out, M);
}